// Round 6
// baseline (290.479 us; speedup 1.0000x reference)
//
#include <hip/hip_runtime.h>

#define DEV __device__ __forceinline__

typedef __attribute__((ext_vector_type(8))) short bf16x8;
typedef __attribute__((ext_vector_type(4))) float f32x4;

static constexpr int Bn = 8;
static constexpr int Sn = 2048;
static constexpr int Dn = 1024;
static constexpr int Mtot = Bn * Sn;   // 16384

// 8-phase GEMM LDS: 2 buffers x (A-half0|A-half1|B-half0|B-half1) x 16KB.
static constexpr int HT = 8192;        // shorts per half-tile (128 rows x 64 k)
static constexpr int BUF = 32768;      // shorts per K-tile buffer

DEV void gload_lds16(const void* g, void* l) {
  __builtin_amdgcn_global_load_lds(
      (const __attribute__((address_space(1))) void*)g,
      (__attribute__((address_space(3))) void*)l, 16, 0, 0);
}

DEV float bf2f(unsigned short u) {
  union { unsigned int i; float f; } c;
  c.i = ((unsigned int)u) << 16;
  return c.f;
}
DEV unsigned short f2bf(float f) {
  union { float f; unsigned int i; } c;
  c.f = f;
  unsigned int lsb = (c.i >> 16) & 1u;
  return (unsigned short)((c.i + 0x7fffu + lsb) >> 16);
}

// ---------------------------------------------------------------- prep
__global__ __launch_bounds__(256) void prep_kernel(const float* __restrict__ x,
                                                   unsigned short* __restrict__ xbf,
                                                   float* __restrict__ masks) {
  const int w = threadIdx.x >> 6, l = threadIdx.x & 63;
  const int row = blockIdx.x * 4 + w;
  const float* xr = x + (size_t)row * Dn;
  unsigned short* xo = xbf + (size_t)row * Dn;
  float s = 0.f;
  #pragma unroll
  for (int i = 0; i < 4; i++) {
    float4 v = ((const float4*)xr)[i * 64 + l];
    s += (v.x + v.y) + (v.z + v.w);
    unsigned int p0 = (unsigned int)f2bf(v.x) | ((unsigned int)f2bf(v.y) << 16);
    unsigned int p1 = (unsigned int)f2bf(v.z) | ((unsigned int)f2bf(v.w) << 16);
    *(uint2*)&xo[i * 256 + l * 4] = make_uint2(p0, p1);
  }
  #pragma unroll
  for (int off = 32; off > 0; off >>= 1) s += __shfl_xor(s, off);
  if (l == 0) masks[row] = sinf(fabsf(s));
}

// ---------------------------------------------------------------- Wt
__global__ __launch_bounds__(256) void wt_kernel(const float* __restrict__ Wq,
                                                 const float* __restrict__ Wk,
                                                 const float* __restrict__ Wv,
                                                 unsigned short* __restrict__ Wt) {
  const float* W = blockIdx.z == 0 ? Wq : (blockIdx.z == 1 ? Wk : Wv);
  unsigned short* out = Wt + (size_t)blockIdx.z * Dn * Dn;
  __shared__ float tile[32][33];
  const int r0 = blockIdx.y * 32, c0 = blockIdx.x * 32;
  const int t = threadIdx.x;
  {
    const int r = t >> 3, c4 = (t & 7) * 4;
    float4 v = *(const float4*)&W[(size_t)(r0 + r) * Dn + c0 + c4];
    tile[r][c4 + 0] = v.x; tile[r][c4 + 1] = v.y;
    tile[r][c4 + 2] = v.z; tile[r][c4 + 3] = v.w;
  }
  __syncthreads();
  {
    const int f = t >> 3, d4 = (t & 7) * 4;
    unsigned short o[4];
    #pragma unroll
    for (int i = 0; i < 4; i++) o[i] = f2bf(tile[d4 + i][f]);
    unsigned int p0 = (unsigned int)o[0] | ((unsigned int)o[1] << 16);
    unsigned int p1 = (unsigned int)o[2] | ((unsigned int)o[3] << 16);
    *(uint2*)&out[(size_t)(c0 + f) * Dn + r0 + d4] = make_uint2(p0, p1);
  }
}

// ------------------------------------------------------------------------
// sync / wait macros: "memory" clobber fences the C++ LDS loads so each
// phase's ds_reads stay issued BEFORE that phase's barrier (latency hides
// under the barrier wait), per the m201 8-phase recipe.
#define BAR   asm volatile("s_barrier" ::: "memory")
#define LGKM0 asm volatile("s_waitcnt lgkmcnt(0)" ::: "memory")
#define LGKM8 asm volatile("s_waitcnt lgkmcnt(8)" ::: "memory")
#define VMC4  asm volatile("s_waitcnt vmcnt(4)" ::: "memory")
#define VMC0  asm volatile("s_waitcnt vmcnt(0)" ::: "memory")

#define MM(d, a, b) d = __builtin_amdgcn_mfma_f32_16x16x32_bf16(a, b, d, 0, 0, 0)

// 16 MFMAs, ks-outer: 8 independent accumulators between reuses of the
// same acc (kills the acc-dependency stall that sank round 5).
#define QUAD(MI0, NI0) do {                                      \
  __builtin_amdgcn_s_setprio(1);                                 \
  MM(acc[(MI0)+0][(NI0)+0], af[0][0], bv[(NI0)+0][0]);           \
  MM(acc[(MI0)+0][(NI0)+1], af[0][0], bv[(NI0)+1][0]);           \
  MM(acc[(MI0)+1][(NI0)+0], af[1][0], bv[(NI0)+0][0]);           \
  MM(acc[(MI0)+1][(NI0)+1], af[1][0], bv[(NI0)+1][0]);           \
  MM(acc[(MI0)+2][(NI0)+0], af[2][0], bv[(NI0)+0][0]);           \
  MM(acc[(MI0)+2][(NI0)+1], af[2][0], bv[(NI0)+1][0]);           \
  MM(acc[(MI0)+3][(NI0)+0], af[3][0], bv[(NI0)+0][0]);           \
  MM(acc[(MI0)+3][(NI0)+1], af[3][0], bv[(NI0)+1][0]);           \
  MM(acc[(MI0)+0][(NI0)+0], af[0][1], bv[(NI0)+0][1]);           \
  MM(acc[(MI0)+0][(NI0)+1], af[0][1], bv[(NI0)+1][1]);           \
  MM(acc[(MI0)+1][(NI0)+0], af[1][1], bv[(NI0)+0][1]);           \
  MM(acc[(MI0)+1][(NI0)+1], af[1][1], bv[(NI0)+1][1]);           \
  MM(acc[(MI0)+2][(NI0)+0], af[2][1], bv[(NI0)+0][1]);           \
  MM(acc[(MI0)+2][(NI0)+1], af[2][1], bv[(NI0)+1][1]);           \
  MM(acc[(MI0)+3][(NI0)+0], af[3][1], bv[(NI0)+0][1]);           \
  MM(acc[(MI0)+3][(NI0)+1], af[3][1], bv[(NI0)+1][1]);           \
  __builtin_amdgcn_s_setprio(0);                                 \
} while (0)

#define RD_AF(BASE, MI0) do {                                    \
  af[0][0] = *(const bf16x8*)((BASE) + offA[(MI0)+0][0]);        \
  af[0][1] = *(const bf16x8*)((BASE) + offA[(MI0)+0][1]);        \
  af[1][0] = *(const bf16x8*)((BASE) + offA[(MI0)+1][0]);        \
  af[1][1] = *(const bf16x8*)((BASE) + offA[(MI0)+1][1]);        \
  af[2][0] = *(const bf16x8*)((BASE) + offA[(MI0)+2][0]);        \
  af[2][1] = *(const bf16x8*)((BASE) + offA[(MI0)+2][1]);        \
  af[3][0] = *(const bf16x8*)((BASE) + offA[(MI0)+3][0]);        \
  af[3][1] = *(const bf16x8*)((BASE) + offA[(MI0)+3][1]);        \
} while (0)

#define RD_BV(BASE, NI0) do {                                    \
  bv[(NI0)+0][0] = *(const bf16x8*)((BASE) + offB[(NI0)+0][0]);  \
  bv[(NI0)+0][1] = *(const bf16x8*)((BASE) + offB[(NI0)+0][1]);  \
  bv[(NI0)+1][0] = *(const bf16x8*)((BASE) + offB[(NI0)+1][0]);  \
  bv[(NI0)+1][1] = *(const bf16x8*)((BASE) + offB[(NI0)+1][1]);  \
} while (0)

// ---------------------------------------------------------------- GEMM core:
// 256x256 tile, BK=64, 8 waves (2Mx4N, per-wave 128x64), 8-phase schedule
// (2 K-tiles / iteration; vmcnt(4) only at phases 4 and 8 — never drains
// mid-loop). Stage targets verified: each staged half-tile's last reader
// retired >=1 barrier earlier. LDS slot permutation per half-tile:
// slot(row,e) = row*8 + (e ^ (row&7)); inverse applied on global source.
DEV void gemm256(const unsigned short* __restrict__ Ag, int lda,
                 const unsigned short* __restrict__ Bg, int ldb,
                 int K, unsigned short* lds, f32x4 acc[8][4]) {
  const int tid = threadIdx.x;
  const int l = tid & 63, w = tid >> 6;
  const int wr = w >> 2, wc = w & 3;
  const int lr = l & 15, lk = l >> 4;

  #pragma unroll
  for (int mi = 0; mi < 8; mi++)
    #pragma unroll
    for (int ni = 0; ni < 4; ni++)
      #pragma unroll
      for (int q = 0; q < 4; q++) acc[mi][ni][q] = 0.f;

  int offA[8][2], offB[4][2];
  #pragma unroll
  for (int mi = 0; mi < 8; mi++)
    #pragma unroll
    for (int ks = 0; ks < 2; ks++) {
      const int row = mi * 16 + lr;
      offA[mi][ks] = (row * 8 + ((ks * 4 + lk) ^ (lr & 7))) * 8;
    }
  #pragma unroll
  for (int ni = 0; ni < 4; ni++)
    #pragma unroll
    for (int ks = 0; ks < 2; ks++) {
      const int rb = (wc & 1) * 64 + ni * 16 + lr;
      offB[ni][ks] = (rb * 8 + ((ks * 4 + lk) ^ (lr & 7))) * 8;
    }
  int sAo[2], sBo[2], dO[2];
  #pragma unroll
  for (int i = 0; i < 2; i++) {
    const int ci = i * 512 + tid;
    const int row = ci >> 3, e = (ci & 7) ^ (row & 7);
    sAo[i] = row * lda + e * 8;
    sBo[i] = row * ldb + e * 8;
    dO[i] = ci * 8;
  }

  const int aOff = wr * HT;
  const int bOff = 2 * HT + (wc >> 1) * HT;

  auto stgA = [&](int half, int kt, unsigned short* buf) {
    const unsigned short* src = Ag + (size_t)half * 128 * lda + kt;
    unsigned short* dst = buf + half * HT;
    gload_lds16(src + sAo[0], dst + dO[0]);
    gload_lds16(src + sAo[1], dst + dO[1]);
  };
  auto stgB = [&](int half, int kt, unsigned short* buf) {
    const unsigned short* src = Bg + (size_t)half * 128 * ldb + kt;
    unsigned short* dst = buf + 2 * HT + half * HT;
    gload_lds16(src + sBo[0], dst + dO[0]);
    gload_lds16(src + sBo[1], dst + dO[1]);
  };

  unsigned short* b0 = lds;
  unsigned short* b1 = lds + BUF;
  const unsigned short* a0c = b0 + aOff;
  const unsigned short* bb0c = b0 + bOff;
  const unsigned short* a1c = b1 + aOff;
  const unsigned short* bb1c = b1 + bOff;
  const int NJ = K >> 7;

  bf16x8 af[4][2], bv[4][2];

  // prologue: tile0 fully; tile1's B0,A0 (the steady-state ph7/ph8 slots)
  stgA(0, 0, b0); stgA(1, 0, b0); stgB(0, 0, b0); stgB(1, 0, b0);
  stgB(0, 64, b1); stgA(0, 64, b1);
  asm volatile("s_waitcnt vmcnt(4)\n\ts_barrier" ::: "memory");

  for (int J = 0; J < NJ; J++) {
    const int kt1  = (2 * J + 1) * 64;
    const int ktn0 = (2 * J + 2) * 64;
    const int ktn1 = (2 * J + 3) * 64;
    const bool more = (J + 1 < NJ);

    // ph1
    RD_AF(a0c, 0); RD_BV(bb0c, 0);
    stgA(1, kt1, b1);
    LGKM8; BAR; LGKM0;
    QUAD(0, 0);
    BAR;
    // ph2
    RD_BV(bb0c, 2);
    stgB(1, kt1, b1);
    BAR; LGKM0;
    QUAD(0, 2);
    BAR;
    // ph3
    RD_AF(a0c, 4);
    if (more) stgB(0, ktn0, b0);
    BAR; LGKM0;
    QUAD(4, 2);
    BAR;
    // ph4
    if (more) stgA(0, ktn0, b0);
    BAR;
    QUAD(4, 0);
    if (more) { VMC4; } else { VMC0; }
    BAR;
    // ph5
    RD_AF(a1c, 0); RD_BV(bb1c, 0);
    if (more) stgA(1, ktn0, b0);
    LGKM8; BAR; LGKM0;
    QUAD(0, 0);
    BAR;
    // ph6
    RD_BV(bb1c, 2);
    if (more) stgB(1, ktn0, b0);
    BAR; LGKM0;
    QUAD(0, 2);
    BAR;
    // ph7
    RD_AF(a1c, 4);
    if (more) stgB(0, ktn1, b1);
    BAR; LGKM0;
    QUAD(4, 2);
    BAR;
    // ph8
    if (more) stgA(0, ktn1, b1);
    BAR;
    QUAD(4, 0);
    if (more) { VMC4; }
    BAR;
  }
}

// ---------------------------------------------------------------- QKV
__global__ __launch_bounds__(512, 2) void qkv_kernel(
    const unsigned short* __restrict__ xbf, const unsigned short* __restrict__ Wt,
    const float* __restrict__ bq, const float* __restrict__ bk,
    const float* __restrict__ bv,
    unsigned short* __restrict__ qo, unsigned short* __restrict__ ko,
    unsigned short* __restrict__ vT) {
  __shared__ __align__(16) unsigned short lds[2 * BUF];
  const int orig = blockIdx.x;                    // 768 blocks
  const int wg = (orig & 7) * 96 + (orig >> 3);   // bijective XCD swizzle
  const int which = wg >> 8;
  const int rem = wg & 255;
  const int m0 = (rem >> 2) * 256, n0 = (rem & 3) * 256;
  const unsigned short* Ag = xbf + (size_t)m0 * Dn;
  const unsigned short* Bg = Wt + (size_t)which * Dn * Dn + (size_t)n0 * Dn;
  f32x4 acc[8][4];
  gemm256(Ag, Dn, Bg, Dn, Dn, lds, acc);

  const float* bias = which == 0 ? bq : (which == 1 ? bk : bv);
  const int tid = threadIdx.x;
  const int l = tid & 63, w = tid >> 6;
  const int wr = w >> 2, wc = w & 3;
  const int lr = l & 15, lk = l >> 4;

  if (which < 2) {
    unsigned short* out = which == 0 ? qo : ko;
    #pragma unroll
    for (int mi = 0; mi < 8; mi++) {
      #pragma unroll
      for (int ni = 0; ni < 4; ni++) {
        const int col = n0 + wc * 64 + ni * 16 + lr;
        const float bcol = bias[col];
        #pragma unroll
        for (int j = 0; j < 4; j++) {
          const int row = m0 + wr * 128 + mi * 16 + lk * 4 + j;
          out[(size_t)row * Dn + col] = f2bf(fmaxf(acc[mi][ni][j] + bcol, 0.f));
        }
      }
    }
  } else {
    // two 128-s halves through a [256 d][128 s] swizzled LDS transpose buffer
    const int b = m0 >> 11;
    const int s0g = m0 & (Sn - 1);
    #pragma unroll 1
    for (int h = 0; h < 2; h++) {
      __syncthreads();   // h=0: staging LDS now dead; h=1: prev reads done
      if (wr == h) {
        #pragma unroll
        for (int mi = 0; mi < 8; mi++) {
          const int sc = mi * 4 + lk;       // 8B chunk of 4 s-values
          #pragma unroll
          for (int ni = 0; ni < 4; ni++) {
            const int d = wc * 64 + ni * 16 + lr;
            const float bcol = bias[n0 + d];
            unsigned short o0 = f2bf(fmaxf(acc[mi][ni][0] + bcol, 0.f));
            unsigned short o1 = f2bf(fmaxf(acc[mi][ni][1] + bcol, 0.f));
            unsigned short o2 = f2bf(fmaxf(acc[mi][ni][2] + bcol, 0.f));
            unsigned short o3 = f2bf(fmaxf(acc[mi][ni][3] + bcol, 0.f));
            const int scp = sc ^ (d & 31);
            *(uint2*)&lds[d * 128 + scp * 4] =
                make_uint2((unsigned int)o0 | ((unsigned int)o1 << 16),
                           (unsigned int)o2 | ((unsigned int)o3 << 16));
          }
        }
      }
      __syncthreads();
      #pragma unroll
      for (int it = 0; it < 16; it++) {
        const int lin = it * 512 + tid;
        const int d = lin >> 5, sc = lin & 31;
        const int scp = sc ^ (d & 31);
        uint2 v = *(const uint2*)&lds[d * 128 + scp * 4];
        *(uint2*)&vT[((size_t)b * Dn + n0 + d) * Sn + s0g + h * 128 + sc * 4] = v;
      }
    }
  }
}

// ---------------------------------------------------------------- scores
__global__ __launch_bounds__(512, 2) void scores_kernel(
    const unsigned short* __restrict__ qbf, const unsigned short* __restrict__ kbf,
    const float* __restrict__ masks, unsigned short* __restrict__ P,
    float* __restrict__ lpart) {
  __shared__ __align__(16) unsigned short lds[2 * BUF];
  const int orig = blockIdx.x;                    // 512 blocks
  const int wg = (orig & 7) * 64 + (orig >> 3);
  const int b = wg >> 6;
  const int rem = wg & 63;
  const int m0 = (rem >> 3) * 256, n0 = (rem & 7) * 256;
  const unsigned short* Ag = qbf + ((size_t)b * Sn + m0) * Dn;
  const unsigned short* Bg = kbf + ((size_t)b * Sn + n0) * Dn;
  f32x4 acc[8][4];
  gemm256(Ag, Dn, Bg, Dn, Dn, lds, acc);

  const int tid = threadIdx.x;
  const int l = tid & 63, w = tid >> 6;
  const int wr = w >> 2, wc = w & 3;
  const int lr = l & 15, lk = l >> 4;

  __syncthreads();               // staging LDS dead; reuse for psum
  float* psum = (float*)lds;     // [4 wc][256 rows]

  float mkv[4];
  #pragma unroll
  for (int ni = 0; ni < 4; ni++) mkv[ni] = masks[b * Sn + n0 + wc * 64 + ni * 16 + lr];

  unsigned short* Pb = P + (size_t)b * Sn * Sn;
  #pragma unroll
  for (int mi = 0; mi < 8; mi++) {
    #pragma unroll
    for (int j = 0; j < 4; j++) {
      const int rloc = wr * 128 + mi * 16 + lk * 4 + j;
      const size_t rbase = (size_t)(m0 + rloc) * Sn;
      float rsum = 0.f;
      #pragma unroll
      for (int ni = 0; ni < 4; ni++) {
        const int col = n0 + wc * 64 + ni * 16 + lr;
        const float p = (mkv[ni] == 0.f) ? 0.f : __expf(acc[mi][ni][j] * 0.03125f);
        const unsigned short pq = f2bf(p);
        Pb[rbase + col] = pq;
        rsum += bf2f(pq);
      }
      rsum += __shfl_xor(rsum, 1); rsum += __shfl_xor(rsum, 2);
      rsum += __shfl_xor(rsum, 4); rsum += __shfl_xor(rsum, 8);
      if (lr == 0) psum[wc * 256 + rloc] = rsum;
    }
  }
  __syncthreads();
  if (tid < 256) {
    const float v = psum[tid] + psum[256 + tid] + psum[512 + tid] + psum[768 + tid];
    lpart[((size_t)b * Sn + m0 + tid) * 8 + (rem & 7)] = v;
  }
}

// ---------------------------------------------------------------- reduce
__global__ __launch_bounds__(256) void reduce_kernel(const float* __restrict__ lpart,
                                                     const float* __restrict__ masks,
                                                     float* __restrict__ scale) {
  const int r = blockIdx.x * 256 + threadIdx.x;
  const float4* p = (const float4*)(lpart + (size_t)r * 8);
  float4 a = p[0], b = p[1];
  const float sum = ((a.x + a.y) + (a.z + a.w)) + ((b.x + b.y) + (b.z + b.w));
  scale[r] = masks[r] / sum;
}

// ---------------------------------------------------------------- PV
__global__ __launch_bounds__(512, 2) void pv_kernel(
    const unsigned short* __restrict__ P, const unsigned short* __restrict__ vT,
    const float* __restrict__ scale, const unsigned short* __restrict__ qbf,
    float* __restrict__ out) {
  __shared__ __align__(16) unsigned short lds[2 * BUF];
  const int orig = blockIdx.x;                    // 256 blocks
  const int wg = (orig & 7) * 32 + (orig >> 3);
  const int b = wg >> 5;
  const int rem = wg & 31;
  const int m0 = (rem >> 2) * 256, n0 = (rem & 3) * 256;
  const unsigned short* Ag = P + (size_t)b * Sn * Sn + (size_t)m0 * Sn;
  const unsigned short* Bg = vT + (size_t)b * Dn * Sn + (size_t)n0 * Sn;
  f32x4 acc[8][4];
  gemm256(Ag, Sn, Bg, Sn, Sn, lds, acc);

  const int tid = threadIdx.x;
  const int l = tid & 63, w = tid >> 6;
  const int wr = w >> 2, wc = w & 3;
  const int lr = l & 15, lk = l >> 4;
  #pragma unroll
  for (int mi = 0; mi < 8; mi++) {
    #pragma unroll
    for (int j = 0; j < 4; j++) {
      const int row = m0 + wr * 128 + mi * 16 + lk * 4 + j;
      const float sc = scale[b * Sn + row];
      const size_t rbase = ((size_t)b * Sn + row) * Dn;
      #pragma unroll
      for (int ni = 0; ni < 4; ni++) {
        const int col = n0 + wc * 64 + ni * 16 + lr;
        out[rbase + col] = acc[mi][ni][j] * sc + bf2f(qbf[rbase + col]);
      }
    }
  }
}

// ---------------------------------------------------------------- launch
extern "C" void kernel_launch(void* const* d_in, const int* in_sizes, int n_in,
                              void* d_out, int out_size, void* d_ws, size_t ws_size,
                              hipStream_t stream) {
  const float* x  = (const float*)d_in[0];
  const float* Wq = (const float*)d_in[1];
  const float* bq = (const float*)d_in[2];
  const float* Wk = (const float*)d_in[3];
  const float* bk = (const float*)d_in[4];
  const float* Wv = (const float*)d_in[5];
  const float* bv = (const float*)d_in[6];
  float* out = (float*)d_out;

  char* ws = (char*)d_ws;
  size_t off = 0;
  auto alloc = [&](size_t bytes) {
    char* p = ws + off;
    off += (bytes + 255) & ~(size_t)255;
    return p;
  };
  unsigned short* xbf = (unsigned short*)alloc((size_t)Mtot * Dn * 2);
  unsigned short* qbf = (unsigned short*)alloc((size_t)Mtot * Dn * 2);
  unsigned short* kbf = (unsigned short*)alloc((size_t)Mtot * Dn * 2);
  unsigned short* vT  = (unsigned short*)alloc((size_t)Bn * Dn * Sn * 2);
  unsigned short* P   = (unsigned short*)alloc((size_t)Bn * Sn * Sn * 2);
  unsigned short* Wt  = (unsigned short*)alloc((size_t)3 * Dn * Dn * 2);
  float* masks = (float*)alloc((size_t)Mtot * 4);
  float* lpart = (float*)alloc((size_t)Mtot * 8 * 4);
  float* scale = (float*)alloc((size_t)Mtot * 4);

  prep_kernel<<<Mtot / 4, 256, 0, stream>>>(x, xbf, masks);
  wt_kernel<<<dim3(32, 32, 3), 256, 0, stream>>>(Wq, Wk, Wv, Wt);
  qkv_kernel<<<768, 512, 0, stream>>>(xbf, Wt, bq, bk, bv, qbf, kbf, vT);
  scores_kernel<<<512, 512, 0, stream>>>(qbf, kbf, masks, P, lpart);
  reduce_kernel<<<Mtot / 256, 256, 0, stream>>>(lpart, masks, scale);
  pv_kernel<<<256, 512, 0, stream>>>(P, vT, scale, qbf, out);
}

// Round 7
// 285.905 us; speedup vs baseline: 1.0160x; 1.0160x over previous
//
#include <hip/hip_runtime.h>

#define DEV __device__ __forceinline__

typedef __attribute__((ext_vector_type(8))) short bf16x8;
typedef __attribute__((ext_vector_type(4))) float f32x4;

static constexpr int Bn = 8;
static constexpr int Sn = 2048;
static constexpr int Dn = 1024;
static constexpr int Mtot = Bn * Sn;   // 16384

// ring-3 LDS, tile 256(M)x128(N), BK=32:
// A 256x32 = 8192 shorts (16KB), B 128x32 = 4096 shorts (8KB) -> 24KB/buf
static constexpr int ABUF = 8192;
static constexpr int TBUF = 12288;     // shorts per ring buffer
// total LDS = 3*24KB = 72KB -> 2 blocks/CU (144KB <= 160KB), 4 waves/SIMD

DEV void gload_lds16(const void* g, void* l) {
  __builtin_amdgcn_global_load_lds(
      (const __attribute__((address_space(1))) void*)g,
      (__attribute__((address_space(3))) void*)l, 16, 0, 0);
}

DEV float bf2f(unsigned short u) {
  union { unsigned int i; float f; } c;
  c.i = ((unsigned int)u) << 16;
  return c.f;
}
DEV unsigned short f2bf(float f) {
  union { float f; unsigned int i; } c;
  c.f = f;
  unsigned int lsb = (c.i >> 16) & 1u;
  return (unsigned short)((c.i + 0x7fffu + lsb) >> 16);
}

// ---------------------------------------------------------------- prep
__global__ __launch_bounds__(256) void prep_kernel(const float* __restrict__ x,
                                                   unsigned short* __restrict__ xbf,
                                                   float* __restrict__ masks) {
  const int w = threadIdx.x >> 6, l = threadIdx.x & 63;
  const int row = blockIdx.x * 4 + w;
  const float* xr = x + (size_t)row * Dn;
  unsigned short* xo = xbf + (size_t)row * Dn;
  float s = 0.f;
  #pragma unroll
  for (int i = 0; i < 4; i++) {
    float4 v = ((const float4*)xr)[i * 64 + l];
    s += (v.x + v.y) + (v.z + v.w);
    unsigned int p0 = (unsigned int)f2bf(v.x) | ((unsigned int)f2bf(v.y) << 16);
    unsigned int p1 = (unsigned int)f2bf(v.z) | ((unsigned int)f2bf(v.w) << 16);
    *(uint2*)&xo[i * 256 + l * 4] = make_uint2(p0, p1);
  }
  #pragma unroll
  for (int off = 32; off > 0; off >>= 1) s += __shfl_xor(s, off);
  if (l == 0) masks[row] = sinf(fabsf(s));
}

// ---------------------------------------------------------------- Wt
__global__ __launch_bounds__(256) void wt_kernel(const float* __restrict__ Wq,
                                                 const float* __restrict__ Wk,
                                                 const float* __restrict__ Wv,
                                                 unsigned short* __restrict__ Wt) {
  const float* W = blockIdx.z == 0 ? Wq : (blockIdx.z == 1 ? Wk : Wv);
  unsigned short* out = Wt + (size_t)blockIdx.z * Dn * Dn;
  __shared__ float tile[32][33];
  const int r0 = blockIdx.y * 32, c0 = blockIdx.x * 32;
  const int t = threadIdx.x;
  {
    const int r = t >> 3, c4 = (t & 7) * 4;
    float4 v = *(const float4*)&W[(size_t)(r0 + r) * Dn + c0 + c4];
    tile[r][c4 + 0] = v.x; tile[r][c4 + 1] = v.y;
    tile[r][c4 + 2] = v.z; tile[r][c4 + 3] = v.w;
  }
  __syncthreads();
  {
    const int f = t >> 3, d4 = (t & 7) * 4;
    unsigned short o[4];
    #pragma unroll
    for (int i = 0; i < 4; i++) o[i] = f2bf(tile[d4 + i][f]);
    unsigned int p0 = (unsigned int)o[0] | ((unsigned int)o[1] << 16);
    unsigned int p1 = (unsigned int)o[2] | ((unsigned int)o[3] << 16);
    *(uint2*)&out[(size_t)(c0 + f) * Dn + r0 + d4] = make_uint2(p0, p1);
  }
}

// ---------------------------------------------------------------- GEMM core:
// 256x128 tile, BK=32, 8 waves (4M x 2N, per-wave 64x64), ring-3 LDS,
// distance-2 staging, counted vmcnt(3) (never drains mid-loop), one barrier
// per tile, 2x8-MFMA setprio clusters (all accs distinct within a tile).
// Swizzle (proven 0-conflict): chunk c' = c ^ ((row>>1)&3), applied on the
// pre-swizzled global SOURCE (linear LDS dest) and on reads.
DEV void gemmtile(const unsigned short* __restrict__ Ag, int lda,
                  const unsigned short* __restrict__ Bg, int ldb,
                  int K, unsigned short* lds, f32x4 acc[4][4]) {
  const int tid = threadIdx.x;
  const int l = tid & 63, w = tid >> 6;
  const int wr = w >> 1, wc = w & 1;
  const int lr = l & 15, lk = l >> 4;

  #pragma unroll
  for (int mi = 0; mi < 4; mi++)
    #pragma unroll
    for (int ni = 0; ni < 4; ni++)
      #pragma unroll
      for (int q = 0; q < 4; q++) acc[mi][ni][q] = 0.f;

  // invariant LDS read offsets (shorts)
  int offA[4], offB[4];
  #pragma unroll
  for (int mi = 0; mi < 4; mi++) {
    const int row = wr * 64 + mi * 16 + lr;
    offA[mi] = (row * 4 + (lk ^ ((row >> 1) & 3))) * 8;
  }
  #pragma unroll
  for (int ni = 0; ni < 4; ni++) {
    const int row = wc * 64 + ni * 16 + lr;
    offB[ni] = (row * 4 + (lk ^ ((row >> 1) & 3))) * 8;
  }
  // invariant stage offsets (A: 2 chunks/thread, B: 1 chunk/thread)
  int sA[2], dA[2], sB, dB;
  #pragma unroll
  for (int i = 0; i < 2; i++) {
    const int ci = i * 512 + tid;
    const int row = ci >> 2, c = (ci & 3) ^ ((row >> 1) & 3);
    sA[i] = row * lda + c * 8;
    dA[i] = ci * 8;
  }
  {
    const int ci = tid;
    const int row = ci >> 2, c = (ci & 3) ^ ((row >> 1) & 3);
    sB = row * ldb + c * 8;
    dB = ci * 8;
  }

  const int NT = K >> 5;
  unsigned short* bc = lds;
  unsigned short* b1 = lds + TBUF;
  unsigned short* b2 = lds + 2 * TBUF;

  // prologue: stage tiles 0,1 (3 loads each); wait tile0 (3 remain).
  #pragma unroll
  for (int t = 0; t < 2; t++) {
    unsigned short* bf = lds + t * TBUF;
    gload_lds16(Ag + sA[0] + t * 32, bf + dA[0]);
    gload_lds16(Ag + sA[1] + t * 32, bf + dA[1]);
    gload_lds16(Bg + sB + t * 32, bf + ABUF + dB);
  }
  asm volatile("s_waitcnt vmcnt(3)\n\ts_barrier" ::: "memory");

  for (int t = 0; t < NT; t++) {
    const bool st = (t + 2 < NT);
    const int kt = (t + 2) * 32;

    bf16x8 af[4], bv[4];
    #pragma unroll
    for (int mi = 0; mi < 4; mi++) af[mi] = *(const bf16x8*)(bc + offA[mi]);
    #pragma unroll
    for (int ni = 0; ni < 4; ni++) bv[ni] = *(const bf16x8*)(bc + ABUF + offB[ni]);

    if (st) {
      gload_lds16(Ag + sA[0] + kt, b2 + dA[0]);
      gload_lds16(Ag + sA[1] + kt, b2 + dA[1]);
    }
    __builtin_amdgcn_s_setprio(1);
    #pragma unroll
    for (int mi = 0; mi < 4; mi++) {
      acc[mi][0] = __builtin_amdgcn_mfma_f32_16x16x32_bf16(af[mi], bv[0], acc[mi][0], 0, 0, 0);
      acc[mi][1] = __builtin_amdgcn_mfma_f32_16x16x32_bf16(af[mi], bv[1], acc[mi][1], 0, 0, 0);
    }
    __builtin_amdgcn_s_setprio(0);
    if (st) {
      gload_lds16(Bg + sB + kt, b2 + ABUF + dB);
    }
    __builtin_amdgcn_s_setprio(1);
    #pragma unroll
    for (int mi = 0; mi < 4; mi++) {
      acc[mi][2] = __builtin_amdgcn_mfma_f32_16x16x32_bf16(af[mi], bv[2], acc[mi][2], 0, 0, 0);
      acc[mi][3] = __builtin_amdgcn_mfma_f32_16x16x32_bf16(af[mi], bv[3], acc[mi][3], 0, 0, 0);
    }
    __builtin_amdgcn_s_setprio(0);

    if (t + 2 < NT) {
      asm volatile("s_waitcnt vmcnt(3)\n\ts_barrier" ::: "memory");
    } else if (t + 1 < NT) {
      asm volatile("s_waitcnt vmcnt(0)\n\ts_barrier" ::: "memory");
    }
    // t == NT-1: no wait/barrier; epilogues sync before LDS reuse.
    unsigned short* tmp = bc; bc = b1; b1 = b2; b2 = tmp;
  }
}

// ---------------------------------------------------------------- QKV
__global__ __launch_bounds__(512, 4) void qkv_kernel(
    const unsigned short* __restrict__ xbf, const unsigned short* __restrict__ Wt,
    const float* __restrict__ bq, const float* __restrict__ bk,
    const float* __restrict__ bv,
    unsigned short* __restrict__ qo, unsigned short* __restrict__ ko,
    unsigned short* __restrict__ vT) {
  __shared__ __align__(16) unsigned short lds[3 * TBUF];
  const int orig = blockIdx.x;                     // 1536 blocks
  const int wg = (orig & 7) * 192 + (orig >> 3);   // bijective XCD swizzle
  const int which = wg >> 9;
  const int rem = wg & 511;
  const int m0 = (rem >> 3) * 256, n0 = (rem & 7) * 128;
  const unsigned short* Ag = xbf + (size_t)m0 * Dn;
  const unsigned short* Bg = Wt + (size_t)which * Dn * Dn + (size_t)n0 * Dn;
  f32x4 acc[4][4];
  gemmtile(Ag, Dn, Bg, Dn, Dn, lds, acc);

  const float* bias = which == 0 ? bq : (which == 1 ? bk : bv);
  const int tid = threadIdx.x;
  const int l = tid & 63, w = tid >> 6;
  const int wr = w >> 1, wc = w & 1;
  const int lr = l & 15, lk = l >> 4;

  if (which < 2) {
    unsigned short* out = which == 0 ? qo : ko;
    #pragma unroll
    for (int mi = 0; mi < 4; mi++) {
      #pragma unroll
      for (int ni = 0; ni < 4; ni++) {
        const int col = n0 + wc * 64 + ni * 16 + lr;
        const float bcol = bias[col];
        #pragma unroll
        for (int j = 0; j < 4; j++) {
          const int row = m0 + wr * 64 + mi * 16 + lk * 4 + j;
          out[(size_t)row * Dn + col] = f2bf(fmaxf(acc[mi][ni][j] + bcol, 0.f));
        }
      }
    }
  } else {
    // single-pass transpose: [128 d][256 s] swizzled LDS buffer (64KB)
    const int b = m0 >> 11;
    const int s0g = m0 & (Sn - 1);
    __syncthreads();  // staging LDS dead
    #pragma unroll
    for (int mi = 0; mi < 4; mi++) {
      const int sc = wr * 16 + mi * 4 + lk;   // 8B chunk of 4 s-values
      #pragma unroll
      for (int ni = 0; ni < 4; ni++) {
        const int d = wc * 64 + ni * 16 + lr;
        const float bcol = bias[n0 + d];
        unsigned short o0 = f2bf(fmaxf(acc[mi][ni][0] + bcol, 0.f));
        unsigned short o1 = f2bf(fmaxf(acc[mi][ni][1] + bcol, 0.f));
        unsigned short o2 = f2bf(fmaxf(acc[mi][ni][2] + bcol, 0.f));
        unsigned short o3 = f2bf(fmaxf(acc[mi][ni][3] + bcol, 0.f));
        const int scp = sc ^ (d & 63);
        *(uint2*)&lds[d * 256 + scp * 4] =
            make_uint2((unsigned int)o0 | ((unsigned int)o1 << 16),
                       (unsigned int)o2 | ((unsigned int)o3 << 16));
      }
    }
    __syncthreads();
    #pragma unroll
    for (int it = 0; it < 16; it++) {
      const int lin = it * 512 + tid;
      const int d = lin >> 6, sc = lin & 63;
      const int scp = sc ^ (d & 63);
      uint2 v = *(const uint2*)&lds[d * 256 + scp * 4];
      *(uint2*)&vT[((size_t)b * Dn + n0 + d) * Sn + s0g + sc * 4] = v;
    }
  }
}

// ---------------------------------------------------------------- scores
__global__ __launch_bounds__(512, 4) void scores_kernel(
    const unsigned short* __restrict__ qbf, const unsigned short* __restrict__ kbf,
    const float* __restrict__ masks, unsigned short* __restrict__ P,
    float* __restrict__ lpart) {
  __shared__ __align__(16) unsigned short lds[3 * TBUF];
  const int orig = blockIdx.x;                     // 1024 blocks
  const int wg = (orig & 7) * 128 + (orig >> 3);
  const int b = wg >> 7;
  const int rem = wg & 127;
  const int m0 = (rem >> 4) * 256, n0 = (rem & 15) * 128;
  const unsigned short* Ag = qbf + ((size_t)b * Sn + m0) * Dn;
  const unsigned short* Bg = kbf + ((size_t)b * Sn + n0) * Dn;
  f32x4 acc[4][4];
  gemmtile(Ag, Dn, Bg, Dn, Dn, lds, acc);

  const int tid = threadIdx.x;
  const int l = tid & 63, w = tid >> 6;
  const int wr = w >> 1, wc = w & 1;
  const int lr = l & 15, lk = l >> 4;

  __syncthreads();               // staging LDS dead; reuse for psum
  float* psum = (float*)lds;     // [2 wc][256 rows]

  float mkv[4];
  #pragma unroll
  for (int ni = 0; ni < 4; ni++) mkv[ni] = masks[b * Sn + n0 + wc * 64 + ni * 16 + lr];

  unsigned short* Pb = P + (size_t)b * Sn * Sn;
  #pragma unroll
  for (int mi = 0; mi < 4; mi++) {
    #pragma unroll
    for (int j = 0; j < 4; j++) {
      const int rloc = wr * 64 + mi * 16 + lk * 4 + j;
      const size_t rbase = (size_t)(m0 + rloc) * Sn;
      float rsum = 0.f;
      #pragma unroll
      for (int ni = 0; ni < 4; ni++) {
        const int col = n0 + wc * 64 + ni * 16 + lr;
        const float p = (mkv[ni] == 0.f) ? 0.f : __expf(acc[mi][ni][j] * 0.03125f);
        const unsigned short pq = f2bf(p);
        Pb[rbase + col] = pq;
        rsum += bf2f(pq);
      }
      rsum += __shfl_xor(rsum, 1); rsum += __shfl_xor(rsum, 2);
      rsum += __shfl_xor(rsum, 4); rsum += __shfl_xor(rsum, 8);
      if (lr == 0) psum[wc * 256 + rloc] = rsum;
    }
  }
  __syncthreads();
  if (tid < 256) {
    const float v = psum[tid] + psum[256 + tid];
    lpart[((size_t)b * Sn + m0 + tid) * 16 + (rem & 15)] = v;
  }
}

// ---------------------------------------------------------------- reduce
__global__ __launch_bounds__(256) void reduce_kernel(const float* __restrict__ lpart,
                                                     const float* __restrict__ masks,
                                                     float* __restrict__ scale) {
  const int r = blockIdx.x * 256 + threadIdx.x;
  const float4* p = (const float4*)(lpart + (size_t)r * 16);
  float4 a = p[0], b = p[1], c = p[2], d = p[3];
  const float sum = ((a.x + a.y) + (a.z + a.w)) + ((b.x + b.y) + (b.z + b.w)) +
                    ((c.x + c.y) + (c.z + c.w)) + ((d.x + d.y) + (d.z + d.w));
  scale[r] = masks[r] / sum;
}

// ---------------------------------------------------------------- PV
__global__ __launch_bounds__(512, 4) void pv_kernel(
    const unsigned short* __restrict__ P, const unsigned short* __restrict__ vT,
    const float* __restrict__ scale, const unsigned short* __restrict__ qbf,
    float* __restrict__ out) {
  __shared__ __align__(16) unsigned short lds[3 * TBUF];
  const int orig = blockIdx.x;                     // 512 blocks
  const int wg = (orig & 7) * 64 + (orig >> 3);
  const int b = wg >> 6;
  const int rem = wg & 63;
  const int m0 = (rem >> 3) * 256, n0 = (rem & 7) * 128;
  const unsigned short* Ag = P + (size_t)b * Sn * Sn + (size_t)m0 * Sn;
  const unsigned short* Bg = vT + (size_t)b * Dn * Sn + (size_t)n0 * Sn;
  f32x4 acc[4][4];
  gemmtile(Ag, Sn, Bg, Sn, Sn, lds, acc);

  const int tid = threadIdx.x;
  const int l = tid & 63, w = tid >> 6;
  const int wr = w >> 1, wc = w & 1;
  const int lr = l & 15, lk = l >> 4;
  #pragma unroll
  for (int mi = 0; mi < 4; mi++) {
    #pragma unroll
    for (int j = 0; j < 4; j++) {
      const int row = m0 + wr * 64 + mi * 16 + lk * 4 + j;
      const float sc = scale[b * Sn + row];
      const size_t rbase = ((size_t)b * Sn + row) * Dn;
      #pragma unroll
      for (int ni = 0; ni < 4; ni++) {
        const int col = n0 + wc * 64 + ni * 16 + lr;
        out[rbase + col] = acc[mi][ni][j] * sc + bf2f(qbf[rbase + col]);
      }
    }
  }
}

// ---------------------------------------------------------------- launch
extern "C" void kernel_launch(void* const* d_in, const int* in_sizes, int n_in,
                              void* d_out, int out_size, void* d_ws, size_t ws_size,
                              hipStream_t stream) {
  const float* x  = (const float*)d_in[0];
  const float* Wq = (const float*)d_in[1];
  const float* bq = (const float*)d_in[2];
  const float* Wk = (const float*)d_in[3];
  const float* bk = (const float*)d_in[4];
  const float* Wv = (const float*)d_in[5];
  const float* bv = (const float*)d_in[6];
  float* out = (float*)d_out;

  char* ws = (char*)d_ws;
  size_t off = 0;
  auto alloc = [&](size_t bytes) {
    char* p = ws + off;
    off += (bytes + 255) & ~(size_t)255;
    return p;
  };
  unsigned short* xbf = (unsigned short*)alloc((size_t)Mtot * Dn * 2);
  unsigned short* qbf = (unsigned short*)alloc((size_t)Mtot * Dn * 2);
  unsigned short* kbf = (unsigned short*)alloc((size_t)Mtot * Dn * 2);
  unsigned short* vT  = (unsigned short*)alloc((size_t)Bn * Dn * Sn * 2);
  unsigned short* P   = (unsigned short*)alloc((size_t)Bn * Sn * Sn * 2);
  unsigned short* Wt  = (unsigned short*)alloc((size_t)3 * Dn * Dn * 2);
  float* masks = (float*)alloc((size_t)Mtot * 4);
  float* lpart = (float*)alloc((size_t)Mtot * 16 * 4);
  float* scale = (float*)alloc((size_t)Mtot * 4);

  prep_kernel<<<Mtot / 4, 256, 0, stream>>>(x, xbf, masks);
  wt_kernel<<<dim3(32, 32, 3), 256, 0, stream>>>(Wq, Wk, Wv, Wt);
  qkv_kernel<<<1536, 512, 0, stream>>>(xbf, Wt, bq, bk, bv, qbf, kbf, vT);
  scores_kernel<<<1024, 512, 0, stream>>>(qbf, kbf, masks, P, lpart);
  reduce_kernel<<<Mtot / 256, 256, 0, stream>>>(lpart, masks, scale);
  pv_kernel<<<512, 512, 0, stream>>>(P, vT, scale, qbf, out);
}